// Round 7
// baseline (474.755 us; speedup 1.0000x reference)
//
#include <hip/hip_runtime.h>
#include <math.h>

#define N_NODES 100000
#define N_EDGES 1200000
#define DIM 64
#define TDIM 32
#define NLAYERS 3
#define NGRAPH 500
#define NP (N_NODES + 1)

#define BUCKW 512                      // nodes per bucket (dst >> 9)
#define NBUCK ((N_NODES + BUCKW - 1) / BUCKW)   // 196
#define ECHUNK ((N_EDGES + 255) / 256)          // 4688 edges per block (256 blocks)
#define MLPBL ((N_NODES + 63) / 64)             // 1563

typedef unsigned short bfu;
typedef __attribute__((ext_vector_type(8))) short short8;
typedef __attribute__((ext_vector_type(4))) float v4f;

__device__ __forceinline__ float bf2f(bfu u) {
    union { unsigned int i; float f; } v; v.i = ((unsigned int)u) << 16; return v.f;
}
__device__ __forceinline__ float bflo(unsigned int d) {
    union { unsigned int i; float f; } v; v.i = d << 16; return v.f;
}
__device__ __forceinline__ float bfhi(unsigned int d) {
    union { unsigned int i; float f; } v; v.i = d & 0xFFFF0000u; return v.f;
}
__device__ __forceinline__ bfu f2bf(float f) {
    union { float f; unsigned int i; } v; v.f = f;
    unsigned int r = v.i + 0x7FFFu + ((v.i >> 16) & 1u);   // RNE
    return (bfu)(r >> 16);
}

// ---------------- merged setup: x->bf16 (blocks 0..6249), graph ranges (6250),
// ---------------- weight transpose+bf16 (6251..6298) ----------------
__global__ __launch_bounds__(256) void k_setup(const float* __restrict__ x, bfu* __restrict__ xb,
                                               const int* __restrict__ gid, int* __restrict__ gstart,
                                               float* __restrict__ inv_safe,
                                               const float* __restrict__ w1, const float* __restrict__ w2,
                                               const float* __restrict__ q1, const float* __restrict__ q2,
                                               bfu* __restrict__ w1t, bfu* __restrict__ w2t,
                                               bfu* __restrict__ q1t, bfu* __restrict__ q2t) {
    int b = blockIdx.x, t = threadIdx.x;
    if (b < 6250) {
        int base = (b * 256 + t) * 4;
        float4 v = *(const float4*)&x[base];
        ushort4 o;
        o.x = f2bf(v.x); o.y = f2bf(v.y); o.z = f2bf(v.z); o.w = f2bf(v.w);
        *(ushort4*)&xb[base] = o;
    } else if (b == 6250) {
        for (int tt = t; tt <= NGRAPH; tt += 256) {
            int lo = 0, hi = N_NODES;
            while (lo < hi) {
                int mid = (lo + hi) >> 1;
                if (gid[mid] < tt) lo = mid + 1; else hi = mid;
            }
            gstart[tt] = lo;
        }
        __syncthreads();
        for (int tt = t; tt < NGRAPH; tt += 256) {
            int c = gstart[tt + 1] - gstart[tt];
            inv_safe[tt] = 1.0f / (float)(c > 1 ? c : 1);
        }
    } else {
        int i = (b - 6251) * 256 + t;     // 0..12287
        int l = i >> 12, k = (i >> 6) & 63, n = i & 63;
        int o = (l << 12) | (n << 6) | k;
        w1t[o] = f2bf(w1[i]);
        w2t[o] = f2bf(w2[i]);
        q1t[o] = f2bf(q1[i]);
        if (i < NLAYERS * 2048) {
            int l2 = i >> 11, rem = i & 2047, k2 = rem >> 5, n2 = rem & 31;
            q2t[l2 * 2048 + n2 * 64 + k2] = f2bf(q2[i]);
        }
    }
}

// ---------------- setup: bucketed CSR build ----------------

__global__ __launch_bounds__(256) void k_bhist(const int* __restrict__ dst, int* __restrict__ bcnt) {
    __shared__ int h[NBUCK];
    int t = threadIdx.x;
    for (int i = t; i < NBUCK; i += 256) h[i] = 0;
    __syncthreads();
    int e0 = blockIdx.x * ECHUNK;
    int e1 = e0 + ECHUNK; if (e1 > N_EDGES) e1 = N_EDGES;
    for (int e = e0 + t; e < e1; e += 256) atomicAdd(&h[dst[e] >> 9], 1);
    __syncthreads();
    for (int i = t; i < NBUCK; i += 256) if (h[i]) atomicAdd(&bcnt[i], h[i]);
}

__global__ __launch_bounds__(256) void k_bscan(const int* __restrict__ bcnt,
                                               int* __restrict__ bbase, int* __restrict__ bcursor) {
    __shared__ int s[256];
    int t = threadIdx.x;
    s[t] = (t < NBUCK) ? bcnt[t] : 0;
    __syncthreads();
    for (int off = 1; off < 256; off <<= 1) {
        int v = (t >= off) ? s[t - off] : 0;
        __syncthreads();
        s[t] += v;
        __syncthreads();
    }
    int ex = t ? s[t - 1] : 0;
    if (t < NBUCK) { bbase[t] = ex; bcursor[t] = ex; }
    if (t == 0) bbase[NBUCK] = N_EDGES;
}

__global__ __launch_bounds__(256) void k_bscatter(const int* __restrict__ src, const int* __restrict__ dst,
                                                  int* __restrict__ bcursor, int2* __restrict__ ebuf) {
    __shared__ int cnt[NBUCK];
    __shared__ int base[NBUCK];
    int t = threadIdx.x;
    for (int i = t; i < NBUCK; i += 256) cnt[i] = 0;
    __syncthreads();
    int e0 = blockIdx.x * ECHUNK;
    int e1 = e0 + ECHUNK; if (e1 > N_EDGES) e1 = N_EDGES;
    for (int e = e0 + t; e < e1; e += 256) atomicAdd(&cnt[dst[e] >> 9], 1);
    __syncthreads();
    for (int i = t; i < NBUCK; i += 256) base[i] = cnt[i] ? atomicAdd(&bcursor[i], cnt[i]) : 0;
    __syncthreads();
    for (int i = t; i < NBUCK; i += 256) cnt[i] = 0;
    __syncthreads();
    for (int e = e0 + t; e < e1; e += 256) {
        int d = dst[e];
        int b = d >> 9;
        int r = atomicAdd(&cnt[b], 1);
        ebuf[base[b] + r] = make_int2(src[e], d);
    }
}

__global__ __launch_bounds__(256) void k_bcsr(const int2* __restrict__ ebuf, const int* __restrict__ bbase,
                                              int* __restrict__ offs, int* __restrict__ csr) {
    __shared__ int ldeg[BUCKW];
    __shared__ int lscan[BUCKW];
    __shared__ int lcur[BUCKW];
    int t = threadIdx.x;
    int b = blockIdx.x;
    int nbase = b << 9;
    int ebeg = bbase[b], eend = bbase[b + 1];
    ldeg[t] = 0; ldeg[t + 256] = 0;
    __syncthreads();
    for (int e = ebeg + t; e < eend; e += 256) atomicAdd(&ldeg[ebuf[e].y - nbase], 1);
    __syncthreads();
    lscan[t] = ldeg[t]; lscan[t + 256] = ldeg[t + 256];
    __syncthreads();
    for (int off = 1; off < BUCKW; off <<= 1) {
        int i0 = t, i1 = t + 256;
        int v0 = (i0 >= off) ? lscan[i0 - off] : 0;
        int v1 = (i1 >= off) ? lscan[i1 - off] : 0;
        __syncthreads();
        lscan[i0] += v0; lscan[i1] += v1;
        __syncthreads();
    }
    int ex0 = lscan[t] - ldeg[t];
    int ex1 = lscan[t + 256] - ldeg[t + 256];
    lcur[t] = ex0; lcur[t + 256] = ex1;
    int n0 = nbase + t, n1 = nbase + t + 256;
    if (n0 < N_NODES) offs[n0] = ebeg + ex0;
    if (n1 < N_NODES) offs[n1] = ebeg + ex1;
    if (b == 0 && t == 0) offs[N_NODES] = N_EDGES;
    __syncthreads();
    for (int e = ebeg + t; e < eend; e += 256) {
        int2 p = ebuf[e];
        int slot = atomicAdd(&lcur[p.y - nbase], 1);
        csr[ebeg + slot] = p.x;
    }
}

// ---------------- per-layer: fused aggregation + conv MLP + stats accumulation ----------------
__device__ __forceinline__ void accum8(float* acc, uint4 d) {
    acc[0] += bflo(d.x); acc[1] += bfhi(d.x);
    acc[2] += bflo(d.y); acc[3] += bfhi(d.y);
    acc[4] += bflo(d.z); acc[5] += bfhi(d.z);
    acc[6] += bflo(d.w); acc[7] += bfhi(d.w);
}

// Per block: 64 nodes, 4 waves. Each wave gathers its own 16 rows into private
// LDS (8 edges in flight per node, nodes serialized), then MFMA MLP:
// GEMM1 -> relu -> LDS transpose -> GEMM2 -> h to global + segmented per-graph
// sum/sumsq atomics (lane=column -> 64 consecutive addresses per atomic inst).
__global__ __launch_bounds__(256, 4) void k_agg_mlp(const bfu* __restrict__ feat,
                                                    const int* __restrict__ offs, const int* __restrict__ csr,
                                                    const float* __restrict__ eps, int l,
                                                    const bfu* __restrict__ w1t, const float* __restrict__ b1,
                                                    const bfu* __restrict__ w2t, const float* __restrict__ b2,
                                                    const int* __restrict__ gid,
                                                    bfu* __restrict__ hout,
                                                    float* __restrict__ gsum, float* __restrict__ gsq) {
    __shared__ bfu ldsT[4][16 * 80];
    __shared__ int sG[4][16];
    int t = threadIdx.x;
    int w = t >> 6, lane = t & 63, m = lane & 15, q = lane >> 4;
    int nbase = blockIdx.x * 64 + w * 16;
    bfu* my = ldsT[w];
    int eidx = lane >> 3, chunk = lane & 7, coff = chunk * 8;
    float ep = 1.0f + eps[l];

    if (lane < 16) sG[w][lane] = (nbase + lane < N_NODES) ? gid[nbase + lane] : -1;

    // ---- gather phase ----
    for (int i = 0; i < 16; i++) {
        int node = nbase + i;
        if (node >= N_NODES) break;            // wave-uniform
        int e0 = offs[node], e1 = offs[node + 1];
        int eL = e1 - 1;
        float acc[8] = {0.f, 0.f, 0.f, 0.f, 0.f, 0.f, 0.f, 0.f};
        for (int e = e0; e < e1; e += 16) {
            int ea = e + eidx;
            int ca = (ea < eL) ? ea : eL;
            int sa = csr[ca];
            uint4 da = *(const uint4*)&feat[sa * DIM + coff];
            bool two = (e + 8) < e1;           // wave-uniform
            if (two) {
                int ebi = e + 8 + eidx;
                int cb = (ebi < eL) ? ebi : eL;
                int sb = csr[cb];
                uint4 db = *(const uint4*)&feat[sb * DIM + coff];
                if (ea >= e1) da = make_uint4(0u, 0u, 0u, 0u);
                if (ebi >= e1) db = make_uint4(0u, 0u, 0u, 0u);
                accum8(acc, da);
                accum8(acc, db);
            } else {
                if (ea >= e1) da = make_uint4(0u, 0u, 0u, 0u);
                accum8(acc, da);
            }
        }
#pragma unroll
        for (int j = 0; j < 8; j++) {
            float v = acc[j];
            v += __shfl_xor(v, 8, 64);
            v += __shfl_xor(v, 16, 64);
            v += __shfl_xor(v, 32, 64);
            acc[j] = v;
        }
        uint4 s = *(const uint4*)&feat[node * DIM + coff];
        float r0 = ep * bflo(s.x) + acc[0], r1 = ep * bfhi(s.x) + acc[1];
        float r2 = ep * bflo(s.y) + acc[2], r3 = ep * bfhi(s.y) + acc[3];
        float r4 = ep * bflo(s.z) + acc[4], r5 = ep * bfhi(s.z) + acc[5];
        float r6 = ep * bflo(s.w) + acc[6], r7 = ep * bfhi(s.w) + acc[7];
        if (eidx == 0) {
            uint4 o;
            o.x = ((unsigned int)f2bf(r1) << 16) | f2bf(r0);
            o.y = ((unsigned int)f2bf(r3) << 16) | f2bf(r2);
            o.z = ((unsigned int)f2bf(r5) << 16) | f2bf(r4);
            o.w = ((unsigned int)f2bf(r7) << 16) | f2bf(r6);
            *(uint4*)&my[i * 80 + coff] = o;
        }
    }

    // ---- B fragments (loaded after gather to limit register pressure there) ----
    short8 bf1[4][2], bf2[4][2];
#pragma unroll
    for (int ct = 0; ct < 4; ct++)
#pragma unroll
        for (int kk = 0; kk < 2; kk++) {
            bf1[ct][kk] = *(const short8*)&w1t[(ct * 16 + m) * 64 + kk * 32 + q * 8];
            bf2[ct][kk] = *(const short8*)&w2t[(ct * 16 + m) * 64 + kk * 32 + q * 8];
        }

    // ---- GEMM1 (A from LDS; overwrite LDS with relu(t_mid) after reading A) ----
    short8 a0 = *(short8*)&my[m * 80 + q * 8];
    short8 a1 = *(short8*)&my[m * 80 + 32 + q * 8];
#pragma unroll
    for (int ct = 0; ct < 4; ct++) {
        float bv = b1[ct * 16 + m];
        v4f acc = {bv, bv, bv, bv};
        acc = __builtin_amdgcn_mfma_f32_16x16x32_bf16(a0, bf1[ct][0], acc, 0, 0, 0);
        acc = __builtin_amdgcn_mfma_f32_16x16x32_bf16(a1, bf1[ct][1], acc, 0, 0, 0);
#pragma unroll
        for (int r = 0; r < 4; r++)
            my[(q * 4 + r) * 80 + ct * 16 + m] = f2bf(fmaxf(acc[r], 0.f));
    }
    // ---- GEMM2 ----
    short8 a20 = *(short8*)&my[m * 80 + q * 8];
    short8 a21 = *(short8*)&my[m * 80 + 32 + q * 8];
#pragma unroll
    for (int ct = 0; ct < 4; ct++) {
        float bv = b2[ct * 16 + m];
        v4f acc = {bv, bv, bv, bv};
        acc = __builtin_amdgcn_mfma_f32_16x16x32_bf16(a20, bf2[ct][0], acc, 0, 0, 0);
        acc = __builtin_amdgcn_mfma_f32_16x16x32_bf16(a21, bf2[ct][1], acc, 0, 0, 0);
#pragma unroll
        for (int r = 0; r < 4; r++)
            my[(q * 4 + r) * 80 + ct * 16 + m] = f2bf(acc[r]);
    }
    // ---- h to global ----
#pragma unroll
    for (int i = 0; i < 2; i++) {
        int idx = i * 64 + lane;
        int r = idx >> 3, ch = (idx & 7) * 8;
        int grow = nbase + r;
        uint4 v = *(uint4*)&my[r * 80 + ch];
        if (grow < N_NODES) *(uint4*)&hout[grow * 64 + ch] = v;
    }
    // ---- per-graph stats accumulation (lane = column) ----
    float s_acc = 0.f, q_acc = 0.f;
    int cur = sG[w][0];
    for (int r = 0; r < 16; r++) {
        int g2 = sG[w][r];
        if (g2 != cur) {
            if (cur >= 0) {
                atomicAdd(&gsum[cur * 64 + lane], s_acc);
                atomicAdd(&gsq[cur * 64 + lane], q_acc);
            }
            cur = g2; s_acc = 0.f; q_acc = 0.f;
        }
        if (g2 >= 0) {
            float v = bf2f(my[r * 80 + lane]);
            s_acc += v; q_acc += v * v;
        }
    }
    if (cur >= 0) {
        atomicAdd(&gsum[cur * 64 + lane], s_acc);
        atomicAdd(&gsq[cur * 64 + lane], q_acc);
    }
}

// ---------------- per-layer: stats finalize (also re-zeroes accumulators) ----------------
__global__ __launch_bounds__(256) void k_stats_fin(const int* __restrict__ gstart,
                                                   const float* __restrict__ inv_safe,
                                                   const float* __restrict__ gnw, const float* __restrict__ gns,
                                                   const float* __restrict__ pb2,
                                                   float* __restrict__ gsum, float* __restrict__ gsq,
                                                   float* __restrict__ gms, float* __restrict__ gcoef,
                                                   float* __restrict__ out, int l) {
    int t = threadIdx.x;
    int g = blockIdx.x * 4 + (t >> 6);   // 125 blocks x 4 graphs
    int c = t & 63;
    int nn = gstart[g + 1] - gstart[g];
    float inv = inv_safe[g];
    float S = gsum[g * 64 + c], Q = gsq[g * 64 + c];
    gsum[g * 64 + c] = 0.f;
    gsq[g * 64 + c] = 0.f;
    float mean = S * inv;
    float ms = mean * gns[c];
    float var = (Q - 2.f * ms * S + (float)nn * ms * ms) * inv;
    gms[g * 64 + c] = ms;
    gcoef[g * 64 + c] = gnw[c] * rsqrtf(var + 1e-8f);
    if (c < TDIM) out[g * (NLAYERS * TDIM) + l * TDIM + c] = (nn > 0) ? pb2[c] : 0.f;
}

// ---------------- per-layer: norm+relu + proj MLP (MFMA) + segmented pooling ----------------
__global__ __launch_bounds__(256) void k_apply_proj(const bfu* __restrict__ h,
                                                    const int* __restrict__ gid,
                                                    const float* __restrict__ gms,
                                                    const float* __restrict__ gcoef,
                                                    const float* __restrict__ gnb,
                                                    const float* __restrict__ inv_safe,
                                                    const bfu* __restrict__ p1t, const float* __restrict__ pb1,
                                                    const bfu* __restrict__ p2t,
                                                    bfu* __restrict__ feat, float* __restrict__ out, int l) {
    __shared__ bfu ldsT[4][16 * 80];
    __shared__ float sZ[64 * 33];
    __shared__ int sGid[64];
    int t = threadIdx.x;
    int w = t >> 6, lane = t & 63, m = lane & 15, q = lane >> 4;
    int row0 = blockIdx.x * 64;
    int row = row0 + w * 16 + m;
    bool valid = row < N_NODES;
    if (t < 64) sGid[t] = (row0 + t < N_NODES) ? gid[row0 + t] : -1;

    union Pack { short8 v; bfu u[8]; uint4 qv; };
    Pack a0, a1;
    a0.qv = make_uint4(0u, 0u, 0u, 0u);
    a1.qv = make_uint4(0u, 0u, 0u, 0u);
    if (valid) {
        int g = gid[row];
#pragma unroll
        for (int kk = 0; kk < 2; kk++) {
            int ch = kk * 32 + q * 8;
            uint4 hv = *(const uint4*)&h[row * 64 + ch];
            float4 msa = *(const float4*)&gms[g * 64 + ch];
            float4 msb = *(const float4*)&gms[g * 64 + ch + 4];
            float4 cfa = *(const float4*)&gcoef[g * 64 + ch];
            float4 cfb = *(const float4*)&gcoef[g * 64 + ch + 4];
            float4 gba = *(const float4*)&gnb[ch];
            float4 gbb = *(const float4*)&gnb[ch + 4];
            Pack& a = kk ? a1 : a0;
            a.u[0] = f2bf(fmaxf(cfa.x * (bflo(hv.x) - msa.x) + gba.x, 0.f));
            a.u[1] = f2bf(fmaxf(cfa.y * (bfhi(hv.x) - msa.y) + gba.y, 0.f));
            a.u[2] = f2bf(fmaxf(cfa.z * (bflo(hv.y) - msa.z) + gba.z, 0.f));
            a.u[3] = f2bf(fmaxf(cfa.w * (bfhi(hv.y) - msa.w) + gba.w, 0.f));
            a.u[4] = f2bf(fmaxf(cfb.x * (bflo(hv.z) - msb.x) + gbb.x, 0.f));
            a.u[5] = f2bf(fmaxf(cfb.y * (bfhi(hv.z) - msb.y) + gbb.y, 0.f));
            a.u[6] = f2bf(fmaxf(cfb.z * (bflo(hv.w) - msb.z) + gbb.z, 0.f));
            a.u[7] = f2bf(fmaxf(cfb.w * (bfhi(hv.w) - msb.w) + gbb.w, 0.f));
            *(uint4*)&feat[row * 64 + ch] = a.qv;
        }
    }

    short8 bf1[4][2], bf2[2][2];
#pragma unroll
    for (int ct = 0; ct < 4; ct++)
#pragma unroll
        for (int kk = 0; kk < 2; kk++)
            bf1[ct][kk] = *(const short8*)&p1t[(ct * 16 + m) * 64 + kk * 32 + q * 8];
#pragma unroll
    for (int ct = 0; ct < 2; ct++)
#pragma unroll
        for (int kk = 0; kk < 2; kk++)
            bf2[ct][kk] = *(const short8*)&p2t[(ct * 16 + m) * 64 + kk * 32 + q * 8];

    bfu* tl = ldsT[w];
#pragma unroll
    for (int ct = 0; ct < 4; ct++) {
        float bv = pb1[ct * 16 + m];
        v4f acc = {bv, bv, bv, bv};
        acc = __builtin_amdgcn_mfma_f32_16x16x32_bf16(a0.v, bf1[ct][0], acc, 0, 0, 0);
        acc = __builtin_amdgcn_mfma_f32_16x16x32_bf16(a1.v, bf1[ct][1], acc, 0, 0, 0);
#pragma unroll
        for (int r = 0; r < 4; r++)
            tl[(q * 4 + r) * 80 + ct * 16 + m] = f2bf(fmaxf(acc[r], 0.f));
    }
    short8 a20 = *(short8*)&tl[m * 80 + q * 8];
    short8 a21 = *(short8*)&tl[m * 80 + 32 + q * 8];
#pragma unroll
    for (int ct = 0; ct < 2; ct++) {
        v4f acc = {0.f, 0.f, 0.f, 0.f};   // pb2 bias pre-written by k_stats_fin
        acc = __builtin_amdgcn_mfma_f32_16x16x32_bf16(a20, bf2[ct][0], acc, 0, 0, 0);
        acc = __builtin_amdgcn_mfma_f32_16x16x32_bf16(a21, bf2[ct][1], acc, 0, 0, 0);
#pragma unroll
        for (int r = 0; r < 4; r++)
            sZ[(w * 16 + q * 4 + r) * 33 + ct * 16 + m] = acc[r];
    }
    __syncthreads();

    if (t < 32) {
        int cur = sGid[0];
        float a = 0.f;
        for (int r = 0; r < 64; r++) {
            int g2 = sGid[r];
            if (g2 != cur) {
                if (cur >= 0) atomicAdd(&out[cur * (NLAYERS * TDIM) + l * TDIM + t], a * inv_safe[cur]);
                cur = g2;
                a = 0.f;
            }
            if (g2 >= 0) a += sZ[r * 33 + t];
        }
        if (cur >= 0) atomicAdd(&out[cur * (NLAYERS * TDIM) + l * TDIM + t], a * inv_safe[cur]);
    }
}

// ---------------- launcher ----------------

extern "C" void kernel_launch(void* const* d_in, const int* in_sizes, int n_in,
                              void* d_out, int out_size, void* d_ws, size_t ws_size,
                              hipStream_t stream) {
    const float* x        = (const float*)d_in[0];
    const int*   src      = (const int*)d_in[1];
    const int*   dst      = (const int*)d_in[2];
    const int*   gid      = (const int*)d_in[3];
    const float* eps      = (const float*)d_in[4];
    const float* conv_w1  = (const float*)d_in[5];
    const float* conv_b1  = (const float*)d_in[6];
    const float* conv_w2  = (const float*)d_in[7];
    const float* conv_b2  = (const float*)d_in[8];
    const float* gn_w     = (const float*)d_in[9];
    const float* gn_b     = (const float*)d_in[10];
    const float* gn_s     = (const float*)d_in[11];
    const float* proj_w1  = (const float*)d_in[12];
    const float* proj_b1  = (const float*)d_in[13];
    const float* proj_w2  = (const float*)d_in[14];
    const float* proj_b2  = (const float*)d_in[15];
    float* out = (float*)d_out;

    char* ws = (char*)d_ws;
    size_t off = 0;
    auto alloc = [&](size_t bytes) { char* p = ws + off; off += (bytes + 255) & ~(size_t)255; return p; };
    int*   offs     = (int*)alloc(NP * sizeof(int));
    int*   gstart   = (int*)alloc((NGRAPH + 1) * sizeof(int));
    float* inv_safe = (float*)alloc(NGRAPH * sizeof(float));
    int*   bcnt     = (int*)alloc(NBUCK * sizeof(int));
    int*   bbase    = (int*)alloc((NBUCK + 1) * sizeof(int));
    int*   bcursor  = (int*)alloc(NBUCK * sizeof(int));
    int*   csr      = (int*)alloc(N_EDGES * sizeof(int));
    bfu*   featbf   = (bfu*)alloc((size_t)N_NODES * DIM * sizeof(bfu));
    bfu*   hbufbf   = (bfu*)alloc((size_t)N_NODES * DIM * sizeof(bfu));
    float* gsum     = (float*)alloc((size_t)NGRAPH * 64 * sizeof(float));   // contiguous with gsq
    float* gsq      = (float*)alloc((size_t)NGRAPH * 64 * sizeof(float));
    float* gms      = (float*)alloc((size_t)NGRAPH * 64 * sizeof(float));
    float* gcoef    = (float*)alloc((size_t)NGRAPH * 64 * sizeof(float));
    bfu*   w1t      = (bfu*)alloc((size_t)NLAYERS * 4096 * sizeof(bfu));
    bfu*   w2t      = (bfu*)alloc((size_t)NLAYERS * 4096 * sizeof(bfu));
    bfu*   p1t      = (bfu*)alloc((size_t)NLAYERS * 4096 * sizeof(bfu));
    bfu*   p2t      = (bfu*)alloc((size_t)NLAYERS * 2048 * sizeof(bfu));
    int2*  ebuf     = (int2*)alloc((size_t)N_EDGES * sizeof(int2));   // setup-only

    // setup
    hipMemsetAsync(bcnt, 0, NBUCK * sizeof(int), stream);
    hipMemsetAsync(gsum, 0, 2 * NGRAPH * 64 * sizeof(float), stream);   // gsum+gsq contiguous
    k_setup<<<6299, 256, 0, stream>>>(x, featbf, gid, gstart, inv_safe,
                                      conv_w1, conv_w2, proj_w1, proj_w2, w1t, w2t, p1t, p2t);
    k_bhist<<<256, 256, 0, stream>>>(dst, bcnt);
    k_bscan<<<1, 256, 0, stream>>>(bcnt, bbase, bcursor);
    k_bscatter<<<256, 256, 0, stream>>>(src, dst, bcursor, ebuf);
    k_bcsr<<<NBUCK, 256, 0, stream>>>(ebuf, bbase, offs, csr);

    for (int l = 0; l < NLAYERS; l++) {
        k_agg_mlp<<<MLPBL, 256, 0, stream>>>(featbf, offs, csr, eps, l,
                                             w1t + l * 4096, conv_b1 + l * 64,
                                             w2t + l * 4096, conv_b2 + l * 64,
                                             gid, hbufbf, gsum, gsq);
        k_stats_fin<<<125, 256, 0, stream>>>(gstart, inv_safe, gn_w + l * 64, gn_s + l * 64,
                                             proj_b2 + l * 32, gsum, gsq, gms, gcoef, out, l);
        k_apply_proj<<<MLPBL, 256, 0, stream>>>(hbufbf, gid, gms, gcoef, gn_b + l * 64,
                                                inv_safe, p1t + l * 4096, proj_b1 + l * 64,
                                                p2t + l * 2048, featbf, out, l);
    }
}

// Round 8
// 442.620 us; speedup vs baseline: 1.0726x; 1.0726x over previous
//
#include <hip/hip_runtime.h>
#include <math.h>

#define N_NODES 100000
#define N_EDGES 1200000
#define DIM 64
#define TDIM 32
#define NLAYERS 3
#define NGRAPH 500
#define NP (N_NODES + 1)

#define BUCKW 512                      // nodes per bucket (dst >> 9)
#define NBUCK ((N_NODES + BUCKW - 1) / BUCKW)   // 196
#define ECHUNK ((N_EDGES + 255) / 256)          // 4688 edges per block (256 blocks)
#define MLPBL ((N_NODES + 63) / 64)             // 1563

typedef unsigned short bfu;
typedef __attribute__((ext_vector_type(8))) short short8;
typedef __attribute__((ext_vector_type(4))) float v4f;

__device__ __forceinline__ float bf2f(bfu u) {
    union { unsigned int i; float f; } v; v.i = ((unsigned int)u) << 16; return v.f;
}
__device__ __forceinline__ float bflo(unsigned int d) {
    union { unsigned int i; float f; } v; v.i = d << 16; return v.f;
}
__device__ __forceinline__ float bfhi(unsigned int d) {
    union { unsigned int i; float f; } v; v.i = d & 0xFFFF0000u; return v.f;
}
__device__ __forceinline__ bfu f2bf(float f) {
    union { float f; unsigned int i; } v; v.f = f;
    unsigned int r = v.i + 0x7FFFu + ((v.i >> 16) & 1u);   // RNE
    return (bfu)(r >> 16);
}

// ---------------- merged setup ----------------
// blocks 0..6249: x->bf16 ; 6250: graph ranges/inv/ncnt ; 6251..6298: weight prep ;
// 6299..6554: bucket histogram (bcnt pre-zeroed by memset, prior dispatch)
__global__ __launch_bounds__(256) void k_setup(const float* __restrict__ x, bfu* __restrict__ xb,
                                               const int* __restrict__ gid, int* __restrict__ gstart,
                                               float* __restrict__ inv_safe, float* __restrict__ ncnt,
                                               const float* __restrict__ w1, const float* __restrict__ w2,
                                               const float* __restrict__ q1, const float* __restrict__ q2,
                                               bfu* __restrict__ w1t, bfu* __restrict__ w2t,
                                               bfu* __restrict__ q1t, bfu* __restrict__ q2t,
                                               const int* __restrict__ dst, int* __restrict__ bcnt) {
    int b = blockIdx.x, t = threadIdx.x;
    if (b < 6250) {
        int base = (b * 256 + t) * 4;
        float4 v = *(const float4*)&x[base];
        ushort4 o;
        o.x = f2bf(v.x); o.y = f2bf(v.y); o.z = f2bf(v.z); o.w = f2bf(v.w);
        *(ushort4*)&xb[base] = o;
    } else if (b == 6250) {
        for (int tt = t; tt <= NGRAPH; tt += 256) {
            int lo = 0, hi = N_NODES;
            while (lo < hi) {
                int mid = (lo + hi) >> 1;
                if (gid[mid] < tt) lo = mid + 1; else hi = mid;
            }
            gstart[tt] = lo;
        }
        __syncthreads();
        for (int tt = t; tt < NGRAPH; tt += 256) {
            int c = gstart[tt + 1] - gstart[tt];
            inv_safe[tt] = 1.0f / (float)(c > 1 ? c : 1);
            ncnt[tt] = (float)c;
        }
    } else if (b < 6299) {
        int i = (b - 6251) * 256 + t;     // 0..12287
        int l = i >> 12, k = (i >> 6) & 63, n = i & 63;
        int o = (l << 12) | (n << 6) | k;
        w1t[o] = f2bf(w1[i]);
        w2t[o] = f2bf(w2[i]);
        q1t[o] = f2bf(q1[i]);
        if (i < NLAYERS * 2048) {
            int l2 = i >> 11, rem = i & 2047, k2 = rem >> 5, n2 = rem & 31;
            q2t[l2 * 2048 + n2 * 64 + k2] = f2bf(q2[i]);
        }
    } else {
        __shared__ int h[NBUCK];
        for (int i = t; i < NBUCK; i += 256) h[i] = 0;
        __syncthreads();
        int e0 = (b - 6299) * ECHUNK;
        int e1 = e0 + ECHUNK; if (e1 > N_EDGES) e1 = N_EDGES;
        for (int e = e0 + t; e < e1; e += 256) atomicAdd(&h[dst[e] >> 9], 1);
        __syncthreads();
        for (int i = t; i < NBUCK; i += 256) if (h[i]) atomicAdd(&bcnt[i], h[i]);
    }
}

// ---------------- setup: bucket scan (+ out-bias pre-write; gstart from prior dispatch) ----------------
__global__ __launch_bounds__(256) void k_bscan(const int* __restrict__ bcnt,
                                               int* __restrict__ bbase, int* __restrict__ bcursor,
                                               const int* __restrict__ gstart,
                                               const float* __restrict__ pb2all, float* __restrict__ out) {
    __shared__ int s[256];
    int t = threadIdx.x;
    s[t] = (t < NBUCK) ? bcnt[t] : 0;
    __syncthreads();
    for (int off = 1; off < 256; off <<= 1) {
        int v = (t >= off) ? s[t - off] : 0;
        __syncthreads();
        s[t] += v;
        __syncthreads();
    }
    int ex = t ? s[t - 1] : 0;
    if (t < NBUCK) { bbase[t] = ex; bcursor[t] = ex; }
    if (t == 0) bbase[NBUCK] = N_EDGES;
    // out-bias pre-write (covers d_out poison; pooling adds atomically later)
    for (int g = t; g < NGRAPH; g += 256) {
        int nn = gstart[g + 1] - gstart[g];
        for (int r = 0; r < NLAYERS * TDIM; r++)
            out[g * (NLAYERS * TDIM) + r] = (nn > 0) ? pb2all[r] : 0.f;
    }
}

__global__ __launch_bounds__(256) void k_bscatter(const int* __restrict__ src, const int* __restrict__ dst,
                                                  int* __restrict__ bcursor, int2* __restrict__ ebuf) {
    __shared__ int cnt[NBUCK];
    __shared__ int base[NBUCK];
    int t = threadIdx.x;
    for (int i = t; i < NBUCK; i += 256) cnt[i] = 0;
    __syncthreads();
    int e0 = blockIdx.x * ECHUNK;
    int e1 = e0 + ECHUNK; if (e1 > N_EDGES) e1 = N_EDGES;
    for (int e = e0 + t; e < e1; e += 256) atomicAdd(&cnt[dst[e] >> 9], 1);
    __syncthreads();
    for (int i = t; i < NBUCK; i += 256) base[i] = cnt[i] ? atomicAdd(&bcursor[i], cnt[i]) : 0;
    __syncthreads();
    for (int i = t; i < NBUCK; i += 256) cnt[i] = 0;
    __syncthreads();
    for (int e = e0 + t; e < e1; e += 256) {
        int d = dst[e];
        int b = d >> 9;
        int r = atomicAdd(&cnt[b], 1);
        ebuf[base[b] + r] = make_int2(src[e], d);
    }
}

__global__ __launch_bounds__(256) void k_bcsr(const int2* __restrict__ ebuf, const int* __restrict__ bbase,
                                              int* __restrict__ offs, int* __restrict__ csr) {
    __shared__ int ldeg[BUCKW];
    __shared__ int lscan[BUCKW];
    __shared__ int lcur[BUCKW];
    int t = threadIdx.x;
    int b = blockIdx.x;
    int nbase = b << 9;
    int ebeg = bbase[b], eend = bbase[b + 1];
    ldeg[t] = 0; ldeg[t + 256] = 0;
    __syncthreads();
    for (int e = ebeg + t; e < eend; e += 256) atomicAdd(&ldeg[ebuf[e].y - nbase], 1);
    __syncthreads();
    lscan[t] = ldeg[t]; lscan[t + 256] = ldeg[t + 256];
    __syncthreads();
    for (int off = 1; off < BUCKW; off <<= 1) {
        int i0 = t, i1 = t + 256;
        int v0 = (i0 >= off) ? lscan[i0 - off] : 0;
        int v1 = (i1 >= off) ? lscan[i1 - off] : 0;
        __syncthreads();
        lscan[i0] += v0; lscan[i1] += v1;
        __syncthreads();
    }
    int ex0 = lscan[t] - ldeg[t];
    int ex1 = lscan[t + 256] - ldeg[t + 256];
    lcur[t] = ex0; lcur[t + 256] = ex1;
    int n0 = nbase + t, n1 = nbase + t + 256;
    if (n0 < N_NODES) offs[n0] = ebeg + ex0;
    if (n1 < N_NODES) offs[n1] = ebeg + ex1;
    if (b == 0 && t == 0) offs[N_NODES] = N_EDGES;
    __syncthreads();
    for (int e = ebeg + t; e < eend; e += 256) {
        int2 p = ebuf[e];
        int slot = atomicAdd(&lcur[p.y - nbase], 1);
        csr[ebeg + slot] = p.x;
    }
}

// ---------------- per-layer: aggregation (standalone: max TLP, 1 wave = 1 node) ----------------
__device__ __forceinline__ void accum8(float* acc, uint4 d) {
    acc[0] += bflo(d.x); acc[1] += bfhi(d.x);
    acc[2] += bflo(d.y); acc[3] += bfhi(d.y);
    acc[4] += bflo(d.z); acc[5] += bfhi(d.z);
    acc[6] += bflo(d.w); acc[7] += bfhi(d.w);
}

__global__ __launch_bounds__(256) void k_agg(const bfu* __restrict__ feat, const int* __restrict__ offs,
                                             const int* __restrict__ csr, const float* __restrict__ eps,
                                             int l, bfu* __restrict__ hin) {
    int w = threadIdx.x >> 6;
    int lane = threadIdx.x & 63;
    int node = blockIdx.x * 4 + w;
    if (node >= N_NODES) return;
    int eidx = lane >> 3;
    int chunk = lane & 7;
    int coff = chunk * 8;
    int e0 = offs[node], e1 = offs[node + 1];
    int eL = e1 - 1;
    float acc[8] = {0.f, 0.f, 0.f, 0.f, 0.f, 0.f, 0.f, 0.f};

    for (int e = e0; e < e1; e += 16) {
        int ea = e + eidx;
        int ca = (ea < eL) ? ea : eL;
        int sa = csr[ca];
        uint4 da = *(const uint4*)&feat[sa * DIM + coff];
        bool two = (e + 8) < e1;
        if (two) {
            int ebi = e + 8 + eidx;
            int cb = (ebi < eL) ? ebi : eL;
            int sb = csr[cb];
            uint4 db = *(const uint4*)&feat[sb * DIM + coff];
            if (ea >= e1) da = make_uint4(0u, 0u, 0u, 0u);
            if (ebi >= e1) db = make_uint4(0u, 0u, 0u, 0u);
            accum8(acc, da);
            accum8(acc, db);
        } else {
            if (ea >= e1) da = make_uint4(0u, 0u, 0u, 0u);
            accum8(acc, da);
        }
    }

#pragma unroll
    for (int j = 0; j < 8; j++) {
        float v = acc[j];
        v += __shfl_xor(v, 8, 64);
        v += __shfl_xor(v, 16, 64);
        v += __shfl_xor(v, 32, 64);
        acc[j] = v;
    }

    float ep = 1.0f + eps[l];
    uint4 s = *(const uint4*)&feat[node * DIM + coff];
    float r0 = ep * bflo(s.x) + acc[0], r1 = ep * bfhi(s.x) + acc[1];
    float r2 = ep * bflo(s.y) + acc[2], r3 = ep * bfhi(s.y) + acc[3];
    float r4 = ep * bflo(s.z) + acc[4], r5 = ep * bfhi(s.z) + acc[5];
    float r6 = ep * bflo(s.w) + acc[6], r7 = ep * bfhi(s.w) + acc[7];
    if (eidx == 0) {
        uint4 o;
        o.x = ((unsigned int)f2bf(r1) << 16) | f2bf(r0);
        o.y = ((unsigned int)f2bf(r3) << 16) | f2bf(r2);
        o.z = ((unsigned int)f2bf(r5) << 16) | f2bf(r4);
        o.w = ((unsigned int)f2bf(r7) << 16) | f2bf(r6);
        *(uint4*)&hin[node * DIM + coff] = o;
    }
}

// ---------------- per-layer: conv MLP via MFMA + per-graph stats atomics ----------------
__global__ __launch_bounds__(256) void k_mlp(const bfu* __restrict__ hin,
                                             const bfu* __restrict__ w1t, const float* __restrict__ b1,
                                             const bfu* __restrict__ w2t, const float* __restrict__ b2,
                                             const int* __restrict__ gid, bfu* __restrict__ hout,
                                             float* __restrict__ gsum, float* __restrict__ gsq) {
    __shared__ bfu ldsT[4][16 * 80];
    __shared__ int sG[4][16];
    int t = threadIdx.x;
    int w = t >> 6, lane = t & 63, m = lane & 15, q = lane >> 4;
    int nbase = blockIdx.x * 64 + w * 16;
    int row = nbase + m;
    bool valid = row < N_NODES;
    if (lane < 16) sG[w][lane] = (nbase + lane < N_NODES) ? gid[nbase + lane] : -1;

    short8 a0 = {0, 0, 0, 0, 0, 0, 0, 0}, a1 = a0;
    if (valid) {
        a0 = *(const short8*)&hin[row * 64 + q * 8];
        a1 = *(const short8*)&hin[row * 64 + 32 + q * 8];
    }
    short8 bf1[4][2], bf2[4][2];
#pragma unroll
    for (int ct = 0; ct < 4; ct++)
#pragma unroll
        for (int kk = 0; kk < 2; kk++) {
            bf1[ct][kk] = *(const short8*)&w1t[(ct * 16 + m) * 64 + kk * 32 + q * 8];
            bf2[ct][kk] = *(const short8*)&w2t[(ct * 16 + m) * 64 + kk * 32 + q * 8];
        }

    bfu* my = ldsT[w];
#pragma unroll
    for (int ct = 0; ct < 4; ct++) {
        float bv = b1[ct * 16 + m];
        v4f acc = {bv, bv, bv, bv};
        acc = __builtin_amdgcn_mfma_f32_16x16x32_bf16(a0, bf1[ct][0], acc, 0, 0, 0);
        acc = __builtin_amdgcn_mfma_f32_16x16x32_bf16(a1, bf1[ct][1], acc, 0, 0, 0);
#pragma unroll
        for (int r = 0; r < 4; r++)
            my[(q * 4 + r) * 80 + ct * 16 + m] = f2bf(fmaxf(acc[r], 0.f));
    }
    short8 a20 = *(short8*)&my[m * 80 + q * 8];
    short8 a21 = *(short8*)&my[m * 80 + 32 + q * 8];
#pragma unroll
    for (int ct = 0; ct < 4; ct++) {
        float bv = b2[ct * 16 + m];
        v4f acc = {bv, bv, bv, bv};
        acc = __builtin_amdgcn_mfma_f32_16x16x32_bf16(a20, bf2[ct][0], acc, 0, 0, 0);
        acc = __builtin_amdgcn_mfma_f32_16x16x32_bf16(a21, bf2[ct][1], acc, 0, 0, 0);
#pragma unroll
        for (int r = 0; r < 4; r++)
            my[(q * 4 + r) * 80 + ct * 16 + m] = f2bf(acc[r]);
    }
#pragma unroll
    for (int i = 0; i < 2; i++) {
        int idx = i * 64 + lane;
        int r = idx >> 3, ch = (idx & 7) * 8;
        int grow = nbase + r;
        uint4 v = *(uint4*)&my[r * 80 + ch];
        if (grow < N_NODES) *(uint4*)&hout[grow * 64 + ch] = v;
    }
    // per-graph stats accumulation (lane = column; ~2 packed atomics/wave)
    float s_acc = 0.f, q_acc = 0.f;
    int cur = sG[w][0];
    for (int r = 0; r < 16; r++) {
        int g2 = sG[w][r];
        if (g2 != cur) {
            if (cur >= 0) {
                atomicAdd(&gsum[cur * 64 + lane], s_acc);
                atomicAdd(&gsq[cur * 64 + lane], q_acc);
            }
            cur = g2; s_acc = 0.f; q_acc = 0.f;
        }
        if (g2 >= 0) {
            float v = bf2f(my[r * 80 + lane]);
            s_acc += v; q_acc += v * v;
        }
    }
    if (cur >= 0) {
        atomicAdd(&gsum[cur * 64 + lane], s_acc);
        atomicAdd(&gsq[cur * 64 + lane], q_acc);
    }
}

// ---------------- per-layer: inline stats finalize + norm+relu + proj MLP + pooling ----------------
__global__ __launch_bounds__(256) void k_apply_proj(const bfu* __restrict__ h,
                                                    const int* __restrict__ gid,
                                                    const float* __restrict__ gsum,
                                                    const float* __restrict__ gsq,
                                                    const float* __restrict__ inv_safe,
                                                    const float* __restrict__ ncnt,
                                                    const float* __restrict__ gnw, const float* __restrict__ gnb,
                                                    const float* __restrict__ gns,
                                                    const bfu* __restrict__ p1t, const float* __restrict__ pb1,
                                                    const bfu* __restrict__ p2t,
                                                    bfu* __restrict__ feat, float* __restrict__ out, int l) {
    __shared__ bfu ldsT[4][16 * 80];
    __shared__ float sZ[64 * 33];
    __shared__ int sGid[64];
    int t = threadIdx.x;
    int w = t >> 6, lane = t & 63, m = lane & 15, q = lane >> 4;
    int row0 = blockIdx.x * 64;
    int row = row0 + w * 16 + m;
    bool valid = row < N_NODES;
    if (t < 64) sGid[t] = (row0 + t < N_NODES) ? gid[row0 + t] : -1;

    union Pack { short8 v; bfu u[8]; uint4 qv; };
    Pack a0, a1;
    a0.qv = make_uint4(0u, 0u, 0u, 0u);
    a1.qv = make_uint4(0u, 0u, 0u, 0u);
    if (valid) {
        int g = gid[row];
        float inv = inv_safe[g];
        float nnf = ncnt[g];
#pragma unroll
        for (int kk = 0; kk < 2; kk++) {
            int ch = kk * 32 + q * 8;
            uint4 hv = *(const uint4*)&h[row * 64 + ch];
            float4 Sa = *(const float4*)&gsum[g * 64 + ch];
            float4 Sb = *(const float4*)&gsum[g * 64 + ch + 4];
            float4 Qa = *(const float4*)&gsq[g * 64 + ch];
            float4 Qb = *(const float4*)&gsq[g * 64 + ch + 4];
            float4 nsa = *(const float4*)&gns[ch];
            float4 nsb = *(const float4*)&gns[ch + 4];
            float4 nwa = *(const float4*)&gnw[ch];
            float4 nwb = *(const float4*)&gnw[ch + 4];
            float4 gba = *(const float4*)&gnb[ch];
            float4 gbb = *(const float4*)&gnb[ch + 4];
            float hval[8] = {bflo(hv.x), bfhi(hv.x), bflo(hv.y), bfhi(hv.y),
                             bflo(hv.z), bfhi(hv.z), bflo(hv.w), bfhi(hv.w)};
            float Sv[8] = {Sa.x, Sa.y, Sa.z, Sa.w, Sb.x, Sb.y, Sb.z, Sb.w};
            float Qv[8] = {Qa.x, Qa.y, Qa.z, Qa.w, Qb.x, Qb.y, Qb.z, Qb.w};
            float nsv[8] = {nsa.x, nsa.y, nsa.z, nsa.w, nsb.x, nsb.y, nsb.z, nsb.w};
            float nwv[8] = {nwa.x, nwa.y, nwa.z, nwa.w, nwb.x, nwb.y, nwb.z, nwb.w};
            float gbv[8] = {gba.x, gba.y, gba.z, gba.w, gbb.x, gbb.y, gbb.z, gbb.w};
            Pack& a = kk ? a1 : a0;
#pragma unroll
            for (int j = 0; j < 8; j++) {
                float ms = Sv[j] * inv * nsv[j];
                float var = (Qv[j] - 2.f * ms * Sv[j] + nnf * ms * ms) * inv;
                float coef = nwv[j] * rsqrtf(var + 1e-8f);
                a.u[j] = f2bf(fmaxf(coef * (hval[j] - ms) + gbv[j], 0.f));
            }
            *(uint4*)&feat[row * 64 + ch] = a.qv;
        }
    }

    short8 bf1[4][2], bf2[2][2];
#pragma unroll
    for (int ct = 0; ct < 4; ct++)
#pragma unroll
        for (int kk = 0; kk < 2; kk++)
            bf1[ct][kk] = *(const short8*)&p1t[(ct * 16 + m) * 64 + kk * 32 + q * 8];
#pragma unroll
    for (int ct = 0; ct < 2; ct++)
#pragma unroll
        for (int kk = 0; kk < 2; kk++)
            bf2[ct][kk] = *(const short8*)&p2t[(ct * 16 + m) * 64 + kk * 32 + q * 8];

    bfu* tl = ldsT[w];
#pragma unroll
    for (int ct = 0; ct < 4; ct++) {
        float bv = pb1[ct * 16 + m];
        v4f acc = {bv, bv, bv, bv};
        acc = __builtin_amdgcn_mfma_f32_16x16x32_bf16(a0.v, bf1[ct][0], acc, 0, 0, 0);
        acc = __builtin_amdgcn_mfma_f32_16x16x32_bf16(a1.v, bf1[ct][1], acc, 0, 0, 0);
#pragma unroll
        for (int r = 0; r < 4; r++)
            tl[(q * 4 + r) * 80 + ct * 16 + m] = f2bf(fmaxf(acc[r], 0.f));
    }
    short8 a20 = *(short8*)&tl[m * 80 + q * 8];
    short8 a21 = *(short8*)&tl[m * 80 + 32 + q * 8];
#pragma unroll
    for (int ct = 0; ct < 2; ct++) {
        v4f acc = {0.f, 0.f, 0.f, 0.f};   // pb2 bias pre-written by k_bscan
        acc = __builtin_amdgcn_mfma_f32_16x16x32_bf16(a20, bf2[ct][0], acc, 0, 0, 0);
        acc = __builtin_amdgcn_mfma_f32_16x16x32_bf16(a21, bf2[ct][1], acc, 0, 0, 0);
#pragma unroll
        for (int r = 0; r < 4; r++)
            sZ[(w * 16 + q * 4 + r) * 33 + ct * 16 + m] = acc[r];
    }
    __syncthreads();

    if (t < 32) {
        int cur = sGid[0];
        float a = 0.f;
        for (int r = 0; r < 64; r++) {
            int g2 = sGid[r];
            if (g2 != cur) {
                if (cur >= 0) atomicAdd(&out[cur * (NLAYERS * TDIM) + l * TDIM + t], a * inv_safe[cur]);
                cur = g2;
                a = 0.f;
            }
            if (g2 >= 0) a += sZ[r * 33 + t];
        }
        if (cur >= 0) atomicAdd(&out[cur * (NLAYERS * TDIM) + l * TDIM + t], a * inv_safe[cur]);
    }
}

// ---------------- launcher ----------------

extern "C" void kernel_launch(void* const* d_in, const int* in_sizes, int n_in,
                              void* d_out, int out_size, void* d_ws, size_t ws_size,
                              hipStream_t stream) {
    const float* x        = (const float*)d_in[0];
    const int*   src      = (const int*)d_in[1];
    const int*   dst      = (const int*)d_in[2];
    const int*   gid      = (const int*)d_in[3];
    const float* eps      = (const float*)d_in[4];
    const float* conv_w1  = (const float*)d_in[5];
    const float* conv_b1  = (const float*)d_in[6];
    const float* conv_w2  = (const float*)d_in[7];
    const float* conv_b2  = (const float*)d_in[8];
    const float* gn_w     = (const float*)d_in[9];
    const float* gn_b     = (const float*)d_in[10];
    const float* gn_s     = (const float*)d_in[11];
    const float* proj_w1  = (const float*)d_in[12];
    const float* proj_b1  = (const float*)d_in[13];
    const float* proj_w2  = (const float*)d_in[14];
    const float* proj_b2  = (const float*)d_in[15];
    float* out = (float*)d_out;

    char* ws = (char*)d_ws;
    size_t off = 0;
    auto alloc = [&](size_t bytes) { char* p = ws + off; off += (bytes + 255) & ~(size_t)255; return p; };
    int*   offs     = (int*)alloc(NP * sizeof(int));
    int*   gstart   = (int*)alloc((NGRAPH + 1) * sizeof(int));
    float* inv_safe = (float*)alloc(NGRAPH * sizeof(float));
    float* ncnt     = (float*)alloc(NGRAPH * sizeof(float));
    // zeroed region: bcnt .. gsumA (one memset covers all, padding included)
    int*   bcnt     = (int*)alloc(NBUCK * sizeof(int));
    float* gsumA    = (float*)alloc((size_t)NLAYERS * 2 * NGRAPH * 64 * sizeof(float));
    size_t zbytes   = (size_t)((char*)(gsumA + (size_t)NLAYERS * 2 * NGRAPH * 64) - (char*)bcnt);
    int*   bbase    = (int*)alloc((NBUCK + 1) * sizeof(int));
    int*   bcursor  = (int*)alloc(NBUCK * sizeof(int));
    int*   csr      = (int*)alloc(N_EDGES * sizeof(int));
    bfu*   featbf   = (bfu*)alloc((size_t)N_NODES * DIM * sizeof(bfu));
    bfu*   hinbf    = (bfu*)alloc((size_t)N_NODES * DIM * sizeof(bfu));
    bfu*   hbufbf   = (bfu*)alloc((size_t)N_NODES * DIM * sizeof(bfu));
    bfu*   w1t      = (bfu*)alloc((size_t)NLAYERS * 4096 * sizeof(bfu));
    bfu*   w2t      = (bfu*)alloc((size_t)NLAYERS * 4096 * sizeof(bfu));
    bfu*   p1t      = (bfu*)alloc((size_t)NLAYERS * 4096 * sizeof(bfu));
    bfu*   p2t      = (bfu*)alloc((size_t)NLAYERS * 2048 * sizeof(bfu));
    int2*  ebuf     = (int2*)alloc((size_t)N_EDGES * sizeof(int2));   // setup-only

    // setup (5 dispatches incl. memset)
    hipMemsetAsync(bcnt, 0, zbytes, stream);
    k_setup<<<6555, 256, 0, stream>>>(x, featbf, gid, gstart, inv_safe, ncnt,
                                      conv_w1, conv_w2, proj_w1, proj_w2, w1t, w2t, p1t, p2t,
                                      dst, bcnt);
    k_bscan<<<1, 256, 0, stream>>>(bcnt, bbase, bcursor, gstart, proj_b2, out);
    k_bscatter<<<256, 256, 0, stream>>>(src, dst, bcursor, ebuf);
    k_bcsr<<<NBUCK, 256, 0, stream>>>(ebuf, bbase, offs, csr);

    int aggbl = (N_NODES + 3) / 4;
    for (int l = 0; l < NLAYERS; l++) {
        float* gsum_l = gsumA + (size_t)l * 2 * NGRAPH * 64;
        float* gsq_l  = gsum_l + NGRAPH * 64;
        k_agg<<<aggbl, 256, 0, stream>>>(featbf, offs, csr, eps, l, hinbf);
        k_mlp<<<MLPBL, 256, 0, stream>>>(hinbf, w1t + l * 4096, conv_b1 + l * 64,
                                         w2t + l * 4096, conv_b2 + l * 64,
                                         gid, hbufbf, gsum_l, gsq_l);
        k_apply_proj<<<MLPBL, 256, 0, stream>>>(hbufbf, gid, gsum_l, gsq_l, inv_safe, ncnt,
                                                gn_w + l * 64, gn_b + l * 64, gn_s + l * 64,
                                                p1t + l * 4096, proj_b1 + l * 64,
                                                p2t + l * 2048, featbf, out, l);
    }
}